// Round 5
// baseline (650.321 us; speedup 1.0000x reference)
//
#include <hip/hip_runtime.h>

#define S_LEN  2048
#define BATCH  1024
#define NL     6
#define CH     16      // timesteps per chunk (x-prefetch granularity)
#define NCHUNK 129     // 129*16 = 2064 >= 2048 + NL - 1 = 2053 steps
#define WPB    8       // waves per block: 2 waves/SIMD -> HW interleaving

typedef float v2f __attribute__((ext_vector_type(2)));

__device__ __forceinline__ float fexp2(float x) { return __builtin_amdgcn_exp2f(x); }
__device__ __forceinline__ float frcp(float x)  { return __builtin_amdgcn_rcpf(x); }

// quad_perm DPP: xor1=[1,0,3,2]=0xB1, xor2=[2,3,0,1]=0x4E, xor3=[3,2,1,0]=0x1B
template <int CTRL>
__device__ __forceinline__ float dppf(float v) {
    return __int_as_float(__builtin_amdgcn_update_dpp(
        0, __float_as_int(v), CTRL, 0xF, 0xF, true));
}
__device__ __forceinline__ float bpermf(int addr, float v) {
    return __int_as_float(__builtin_amdgcn_ds_bpermute(addr, __float_as_int(v)));
}
__device__ __forceinline__ float sigf(float x)  { return frcp(1.0f + fexp2(x * -1.442695041f)); }
__device__ __forceinline__ float tanh_(float x) { return fmaf(2.0f, frcp(1.0f + fexp2(x * -2.885390082f)), -1.0f); }

// ONE wave carries the whole 6-layer pipeline for 2 batch elements.
// lane = L*8 + e*4 + j (L=layer 0..5; lanes 48-55 idle; lanes 56-63 feeders
// whose h register holds x[t]). Skew-1: at step n, layer L computes t = n-L;
// handoff via one ds_bpermute (src = lane-8, L0 pulls feeders at lane+56).
// Gate math packed as float2 {i,f},{g,o} -> v_pk_fma_f32 (16 instead of 32).
// 8 independent waves per block (no barriers/LDS) -> 2 waves/SIMD so the
// sibling wave's issue fills this wave's dependency stalls.
__global__ __launch_bounds__(64 * WPB, 1) void lstm_wavepipe3(
    const float* __restrict__ x, const float* __restrict__ w_ih,
    const float* __restrict__ w_hh, const float* __restrict__ b_ih,
    const float* __restrict__ b_hh, const float* __restrict__ reg_w,
    const float* __restrict__ reg_b, float* __restrict__ out) {
    const int wave = threadIdx.x >> 6;
    const int lane = threadIdx.x & 63;
    const int L    = lane >> 3;
    const int e    = (lane >> 2) & 1;
    const int j    = lane & 3;
    const int b    = (blockIdx.x * WPB + wave) * 2 + e;
    const int Lc   = (L < NL) ? L : NL - 1;      // clamp for safe weight loads
    const bool isFeeder = (lane >= 56);
    const bool isOut    = (L == 5) && (j == 0);

    // ---- weight preload: packed pairs p=0 -> gates (i,f), p=1 -> (g,o);
    //      term m multiplies value of unit j^m ----
    v2f Wx2[2][4], Wh2[2][4], Gb2[2];
#pragma unroll
    for (int p = 0; p < 2; ++p) {
        const int ra = Lc * 16 + (2 * p) * 4 + j;      // PyTorch order i,f,g,o
        const int rb = Lc * 16 + (2 * p + 1) * 4 + j;
#pragma unroll
        for (int m = 0; m < 4; ++m) {
            Wx2[p][m] = (v2f){w_ih[ra * 4 + (j ^ m)], w_ih[rb * 4 + (j ^ m)]};
            Wh2[p][m] = (v2f){w_hh[ra * 4 + (j ^ m)], w_hh[rb * 4 + (j ^ m)]};
        }
        Gb2[p] = (v2f){b_ih[ra] + b_hh[ra], b_ih[rb] + b_hh[rb]};
    }
    const float regw = reg_w[j];
    const float regb = reg_b[0];
    const int bpaddr = ((lane >= 8) ? (lane - 8) : (lane + 56)) << 2;
    // after ++ at step n: tc = n - L; non-compute lanes never activate
    int tc = (L < NL) ? (-L - 1) : -2100000000;

    float h = 0.0f, c = 0.0f;
    float xu[CH], xp[CH], su[CH];
    const size_t xoff = (size_t)(b * 4 + j);     // x[t*4096 + 4b + j]

#pragma unroll
    for (int u = 0; u < CH; ++u) xu[u] = x[(size_t)u * 4096 + xoff];

    for (int cc = 0; cc < NCHUNK; ++cc) {
        // ---- prefetch next chunk's x (lands during the 16 steps below) ----
#pragma unroll
        for (int u = 0; u < CH; ++u) {
            int t2 = (cc + 1) * CH + u;
            if (t2 > S_LEN - 1) t2 = S_LEN - 1;
            xp[u] = x[(size_t)t2 * 4096 + xoff];
        }
        // ---- 16 pipeline steps: registers + 1 bpermute + 8 DPP per step ----
#pragma unroll
        for (int u = 0; u < CH; ++u) {
            ++tc;
            h = isFeeder ? xu[u] : h;            // feeders publish x[n]
            const float hup = bpermf(bpaddr, h); // h from layer above (or x)
            const float hv1 = dppf<0xB1>(h),   hv2 = dppf<0x4E>(h),   hv3 = dppf<0x1B>(h);
            const float xv1 = dppf<0xB1>(hup), xv2 = dppf<0x4E>(hup), xv3 = dppf<0x1B>(hup);
            v2f A0 = Gb2[0], A1 = Gb2[1];
            // own-h terms first (independent of bpermute -> hides lgkm latency)
            { v2f s = {h,   h  }; A0 = A0 + Wh2[0][0] * s; A1 = A1 + Wh2[1][0] * s; }
            { v2f s = {hv1, hv1}; A0 = A0 + Wh2[0][1] * s; A1 = A1 + Wh2[1][1] * s; }
            { v2f s = {hv2, hv2}; A0 = A0 + Wh2[0][2] * s; A1 = A1 + Wh2[1][2] * s; }
            { v2f s = {hv3, hv3}; A0 = A0 + Wh2[0][3] * s; A1 = A1 + Wh2[1][3] * s; }
            { v2f s = {hup, hup}; A0 = A0 + Wx2[0][0] * s; A1 = A1 + Wx2[1][0] * s; }
            { v2f s = {xv1, xv1}; A0 = A0 + Wx2[0][1] * s; A1 = A1 + Wx2[1][1] * s; }
            { v2f s = {xv2, xv2}; A0 = A0 + Wx2[0][2] * s; A1 = A1 + Wx2[1][2] * s; }
            { v2f s = {xv3, xv3}; A0 = A0 + Wx2[0][3] * s; A1 = A1 + Wx2[1][3] * s; }
            const float si = sigf(A0.x);
            const float sf = sigf(A0.y);
            const float tg = tanh_(A1.x);
            const float so = sigf(A1.y);
            const float cn = fmaf(sf, c, si * tg);
            const float hn = so * tanh_(cn);
            const bool act = (unsigned)tc < (unsigned)S_LEN;
            c = act ? cn : c;
            h = act ? hn : h;
            // linear head (valid on L5 lanes; buffered, stored at chunk end)
            float s = h * regw;
            s += dppf<0xB1>(s);
            s += dppf<0x4E>(s);
            su[u] = s + regb;
        }
        // ---- drain head outputs for this chunk ----
        if (isOut) {
            const int base = cc * CH - (NL - 1);
#pragma unroll
            for (int u = 0; u < CH; ++u) {
                const int t = base + u;
                if (t >= 0 && t < S_LEN) out[(size_t)t * BATCH + b] = su[u];
            }
        }
        // ---- rotate prefetch buffer ----
#pragma unroll
        for (int u = 0; u < CH; ++u) xu[u] = xp[u];
    }
}

extern "C" void kernel_launch(void* const* d_in, const int* in_sizes, int n_in,
                              void* d_out, int out_size, void* d_ws, size_t ws_size,
                              hipStream_t stream) {
    const float* x     = (const float*)d_in[0];
    const float* w_ih  = (const float*)d_in[1];
    const float* w_hh  = (const float*)d_in[2];
    const float* b_ih  = (const float*)d_in[3];
    const float* b_hh  = (const float*)d_in[4];
    const float* reg_w = (const float*)d_in[5];
    const float* reg_b = (const float*)d_in[6];
    float* out = (float*)d_out;

    // 64 blocks x 8 waves: 2 waves/SIMD on 64 CUs -> HW wave interleaving
    // fills each wave's ~350-cycle dependency stalls with sibling issue.
    dim3 grid(BATCH / (2 * WPB));
    dim3 block(64 * WPB);
    hipLaunchKernelGGL(lstm_wavepipe3, grid, block, 0, stream, x, w_ih, w_hh,
                       b_ih, b_hh, reg_w, reg_b, out);
}

// Round 6
// 515.766 us; speedup vs baseline: 1.2609x; 1.2609x over previous
//
#include <hip/hip_runtime.h>

#define S_LEN  2048
#define BATCH  1024
#define NL     6
#define CH     16      // timesteps per chunk (x-prefetch granularity)
#define NCHUNK 129     // 129*16 = 2064 >= 2048 + NL - 1 = 2053 steps

__device__ __forceinline__ float fexp2(float x) { return __builtin_amdgcn_exp2f(x); }
__device__ __forceinline__ float frcp(float x)  { return __builtin_amdgcn_rcpf(x); }

// quad_perm DPP: xor1=[1,0,3,2]=0xB1, xor2=[2,3,0,1]=0x4E, xor3=[3,2,1,0]=0x1B
template <int CTRL>
__device__ __forceinline__ float dppf(float v) {
    return __int_as_float(__builtin_amdgcn_update_dpp(
        0, __float_as_int(v), CTRL, 0xF, 0xF, true));
}
__device__ __forceinline__ float bpermf(int addr, float v) {
    return __int_as_float(__builtin_amdgcn_ds_bpermute(addr, __float_as_int(v)));
}
__device__ __forceinline__ float sigf(float x)  { return frcp(1.0f + fexp2(x * -1.442695041f)); }
__device__ __forceinline__ float tanh_(float x) { return fmaf(2.0f, frcp(1.0f + fexp2(x * -2.885390082f)), -1.0f); }

// ONE wave carries the whole 6-layer pipeline for 2 batch elements.
// lane = L*8 + e*4 + j (L=layer 0..5; lanes 48-55 idle; lanes 56-63 feeders
// whose published h holds x[t]). Skew-1: at step n, layer L computes t=n-L.
// KEY vs R3: the handoff ds_bpermute is issued at the END of step n (as soon
// as h(t) exists) and consumed AFTER step n+1's own-h section -> its ~120cyc
// LDS-pipe latency is covered by ~130 cyc of independent issue, and it is the
// ONLY outstanding DS op, so the compiler's lgkmcnt(0) waits exactly on it.
// Gate accumulation split into two 4-deep chains (h-side / x-side) + 1 add.
// Head reduce deferred to the chunk drain (su[u]=h is 1 mov in-loop).
template <bool GUARD>
__device__ __forceinline__ void run_chunk(
    int cc, int& tc, float& h, float& c, float& hup_next,
    const float (&Wx)[4][4], const float (&Wh)[4][4], const float (&Gb)[4],
    float (&xu)[CH], float regw, float regb, int bpaddr, bool isFeeder,
    bool isOut, int b, size_t xoff, const float* __restrict__ x,
    float* __restrict__ out) {
    float xp[CH];
    // prefetch next chunk's x (feeder value for step n is x[n+1])
#pragma unroll
    for (int u = 0; u < CH; ++u) {
        int t2 = (cc + 1) * CH + u + 1;
        if (t2 > S_LEN - 1) t2 = S_LEN - 1;
        xp[u] = x[(size_t)t2 * 4096 + xoff];
    }
    float su[CH];
#pragma unroll
    for (int u = 0; u < CH; ++u) {
        // ---- own-h section first: independent of the in-flight bpermute ----
        const float hv1 = dppf<0xB1>(h), hv2 = dppf<0x4E>(h), hv3 = dppf<0x1B>(h);
        float Hi = Gb[0], Hf = Gb[1], Hg = Gb[2], Ho = Gb[3];
        Hi = fmaf(Wh[0][0], h, Hi);   Hf = fmaf(Wh[1][0], h, Hf);
        Hg = fmaf(Wh[2][0], h, Hg);   Ho = fmaf(Wh[3][0], h, Ho);
        Hi = fmaf(Wh[0][1], hv1, Hi); Hf = fmaf(Wh[1][1], hv1, Hf);
        Hg = fmaf(Wh[2][1], hv1, Hg); Ho = fmaf(Wh[3][1], hv1, Ho);
        Hi = fmaf(Wh[0][2], hv2, Hi); Hf = fmaf(Wh[1][2], hv2, Hf);
        Hg = fmaf(Wh[2][2], hv2, Hg); Ho = fmaf(Wh[3][2], hv2, Ho);
        Hi = fmaf(Wh[0][3], hv3, Hi); Hf = fmaf(Wh[1][3], hv3, Hf);
        Hg = fmaf(Wh[2][3], hv3, Hg); Ho = fmaf(Wh[3][3], hv3, Ho);
        // ---- consume the bpermute issued at the end of the previous step ----
        const float hup = hup_next;
        const float xv1 = dppf<0xB1>(hup), xv2 = dppf<0x4E>(hup), xv3 = dppf<0x1B>(hup);
        float Xi = Wx[0][0] * hup,  Xf = Wx[1][0] * hup;
        float Xg = Wx[2][0] * hup,  Xo = Wx[3][0] * hup;
        Xi = fmaf(Wx[0][1], xv1, Xi); Xf = fmaf(Wx[1][1], xv1, Xf);
        Xg = fmaf(Wx[2][1], xv1, Xg); Xo = fmaf(Wx[3][1], xv1, Xo);
        Xi = fmaf(Wx[0][2], xv2, Xi); Xf = fmaf(Wx[1][2], xv2, Xf);
        Xg = fmaf(Wx[2][2], xv2, Xg); Xo = fmaf(Wx[3][2], xv2, Xo);
        Xi = fmaf(Wx[0][3], xv3, Xi); Xf = fmaf(Wx[1][3], xv3, Xf);
        Xg = fmaf(Wx[2][3], xv3, Xg); Xo = fmaf(Wx[3][3], xv3, Xo);
        const float si = sigf(Hi + Xi);
        const float sf = sigf(Hf + Xf);
        const float tg = tanh_(Hg + Xg);
        const float so = sigf(Ho + Xo);
        const float cn = fmaf(sf, c, si * tg);
        const float hn = so * tanh_(cn);
        if (GUARD) {
            ++tc;
            const bool act = (unsigned)tc < (unsigned)S_LEN;
            c = act ? cn : c;
            h = act ? hn : h;
        } else {
            c = cn;   // tail corruption is harmless: h is published before a
            h = hn;   // lane's own invalid range; out-of-range su never stored
        }
        h = isFeeder ? xu[u] : h;        // feeders publish x[n+1]
        hup_next = bpermf(bpaddr, h);    // issued NOW, consumed next step
        su[u] = h;                       // L5 lanes: == hn (not feeders)
    }
    // ---- chunk drain: head reduce + store (16 independent chains) ----
    const int base = cc * CH - (NL - 1);
#pragma unroll
    for (int u = 0; u < CH; ++u) {
        float s = su[u] * regw;
        s += dppf<0xB1>(s);
        s += dppf<0x4E>(s);
        s += regb;
        const int t = base + u;
        if (isOut && t >= 0 && t < S_LEN) out[(size_t)t * BATCH + b] = s;
    }
    // ---- rotate prefetch buffer ----
#pragma unroll
    for (int u = 0; u < CH; ++u) xu[u] = xp[u];
}

__global__ __launch_bounds__(64, 1) void lstm_wavepipe4(
    const float* __restrict__ x, const float* __restrict__ w_ih,
    const float* __restrict__ w_hh, const float* __restrict__ b_ih,
    const float* __restrict__ b_hh, const float* __restrict__ reg_w,
    const float* __restrict__ reg_b, float* __restrict__ out) {
    const int lane = threadIdx.x;
    const int L    = lane >> 3;
    const int e    = (lane >> 2) & 1;
    const int j    = lane & 3;
    const int b    = blockIdx.x * 2 + e;
    const int Lc   = (L < NL) ? L : NL - 1;      // clamp for safe weight loads
    const bool isFeeder = (lane >= 56);
    const bool isOut    = (L == 5) && (j == 0);

    // ---- weight preload, permuted so term m multiplies value of unit j^m ----
    float Wx[4][4], Wh[4][4], Gb[4];
#pragma unroll
    for (int g = 0; g < 4; ++g) {
        const int row = Lc * 16 + g * 4 + j;     // PyTorch gate order i,f,g,o
#pragma unroll
        for (int m = 0; m < 4; ++m) {
            Wx[g][m] = w_ih[row * 4 + (j ^ m)];
            Wh[g][m] = w_hh[row * 4 + (j ^ m)];
        }
        Gb[g] = b_ih[row] + b_hh[row];
    }
    const float regw = reg_w[j];
    const float regb = reg_b[0];
    const int bpaddr = ((lane >= 8) ? (lane - 8) : (lane + 56)) << 2;
    // after ++ at step n: tc = n - L; non-compute lanes never activate
    int tc = (L < NL) ? (-L - 1) : -2100000000;

    float h = 0.0f, c = 0.0f;
    float xu[CH];
    const size_t xoff = (size_t)(b * 4 + j);     // x[t*4096 + 4b + j]

    // xu[u] holds x[u+1] (feeder publishes x[n+1] at end of step n)
#pragma unroll
    for (int u = 0; u < CH; ++u) {
        int t2 = u + 1; if (t2 > S_LEN - 1) t2 = S_LEN - 1;
        xu[u] = x[(size_t)t2 * 4096 + xoff];
    }
    // prime the handoff: step-0 inputs (L0 <- x[0]; L>0 <- h=0)
    float hup_next;
    {
        const float fh = isFeeder ? x[xoff] : 0.0f;
        hup_next = bpermf(bpaddr, fh);
    }

    run_chunk<true>(0, tc, h, c, hup_next, Wx, Wh, Gb, xu, regw, regb,
                    bpaddr, isFeeder, isOut, b, xoff, x, out);
    for (int cc = 1; cc < NCHUNK; ++cc)
        run_chunk<false>(cc, tc, h, c, hup_next, Wx, Wh, Gb, xu, regw, regb,
                         bpaddr, isFeeder, isOut, b, xoff, x, out);
}

extern "C" void kernel_launch(void* const* d_in, const int* in_sizes, int n_in,
                              void* d_out, int out_size, void* d_ws, size_t ws_size,
                              hipStream_t stream) {
    const float* x     = (const float*)d_in[0];
    const float* w_ih  = (const float*)d_in[1];
    const float* w_hh  = (const float*)d_in[2];
    const float* b_ih  = (const float*)d_in[3];
    const float* b_hh  = (const float*)d_in[4];
    const float* reg_w = (const float*)d_in[5];
    const float* reg_b = (const float*)d_in[6];
    float* out = (float*)d_out;

    dim3 grid(BATCH / 2);   // 512 single-wave blocks: 1 wave/SIMD chip-wide
    dim3 block(64);
    hipLaunchKernelGGL(lstm_wavepipe4, grid, block, 0, stream, x, w_ih, w_hh,
                       b_ih, b_hh, reg_w, reg_b, out);
}